// Round 7
// baseline (184.104 us; speedup 1.0000x reference)
//
#include <hip/hip_runtime.h>
#include <hip/hip_bf16.h>

// y_i = x_i^T Q x_i + b^T x_i + c ; N=16384, D=1024, fp32.
// Round 11: Q out of LDS, barrier-free rounds. R10 pipe arithmetic:
// 3200 cyc/round vs ~1500 cyc LDS-pipe (B-frags read 2x: 64KB + staging
// 32KB + dot 16KB + 4.2M conflicts) + per-round barrier at 2 waves/SIMD
// -> LDS+barrier bound. Restructure:
//  - 8 waves own DISJOINT k-eighths (128k) of all 64 rows (a[4][4] = 64
//    AGPR, same count as R10's a[2][8]). B-frags are wave-private ->
//    loaded DIRECT from L2 to registers. No tile LDS, no staging, no
//    per-round barrier. L2: 32KB/CU/round (tile read once).
//  - cvt pass emits qb FRAG-ORDERED: seg(tile,eighth) = contiguous 4KB,
//    lane load = seg + lane*16 + s*1024 -> fully coalesced (fixes R9's
//    2KB-stride scatter). B regs double-buffered as NAMED SCALARS
//    (bA0..3/bB0..3) - zero array indexing, no scratch risk (rule 20).
//  - LDS keeps only xv (f32, 67.6KB; dot reads 2-way = free) + yred.
//    Barriers: 9 total (8 phase boundaries + prologue). Waves free-run
//    within a phase; latency hides via wave slip + reg dbuf.
// Est ~95 VGPR + 64 AGPR ~ 160 unified @ (512,2) budget 256.
// Grid 256 = 1 block/CU; full-K blocks -> direct y stores, no memset.
// Tripwire: WRITE_SIZE >> 2.2MB means spill -> revert to single-buf B.

#define DD 1024
#define XR 132                 // xv row stride in floats (128 + 4)

typedef short v8s __attribute__((ext_vector_type(8)));
typedef float v4f __attribute__((ext_vector_type(4)));

__device__ __forceinline__ short f2b(float f) {
    union { __hip_bfloat16 h; short s; } u;
    u.h = __float2bfloat16(f);
    return u.s;
}
__device__ __forceinline__ float b2f(short s) {
    union { unsigned u; float f; } uu;
    uu.u = ((unsigned)(unsigned short)s) << 16;
    return uu.f;
}

#define MFMA16(A, B, C) __builtin_amdgcn_mfma_f32_16x16x32_bf16(A, B, C, 0, 0, 0)

// pass 1: Q fp32 -> bf16, frag-ordered segments in d_ws (2 MB).
// Element Q[n][k] -> seg (t = n>>4, e = k>>7), byte s*1024 + lane*16 + j*2
// where s = (k&127)>>5, quad = (k&31)>>3, j = k&7, lane = quad*16 + (n&15).
__global__ __launch_bounds__(256, 4)
void cvt_kernel(const float* __restrict__ Q, char* __restrict__ qb)
{
    const int gid = blockIdx.x * 256 + threadIdx.x;   // 131072 threads
    const int n  = gid >> 7;          // Q row 0..1023
    const int k8 = gid & 127;         // 8-elem group within row
    const float4 f0 = *(const float4*)(Q + (size_t)n * DD + k8 * 8);
    const float4 f1 = *(const float4*)(Q + (size_t)n * DD + k8 * 8 + 4);
    v8s t;
    t[0]=f2b(f0.x); t[1]=f2b(f0.y); t[2]=f2b(f0.z); t[3]=f2b(f0.w);
    t[4]=f2b(f1.x); t[5]=f2b(f1.y); t[6]=f2b(f1.z); t[7]=f2b(f1.w);
    const int tt = n >> 4, l15 = n & 15;
    const int e = k8 >> 4, rem = k8 & 15, s = rem >> 2, quad = rem & 3;
    char* dst = qb + ((size_t)(tt * 8 + e) << 12) + s * 1024 + (quad * 16 + l15) * 16;
    *(v8s*)dst = t;
}

// load the 4 B-frags (one k-eighth x 16 cols) for tile T
#define LOADB(B0, B1, B2, B3, T)                                          \
  { const char* p_ = qb + ((size_t)((T) * 8 + e) << 12) + lane * 16;      \
    B0 = *(const v8s*)(p_);                                               \
    B1 = *(const v8s*)(p_ + 1024);                                        \
    B2 = *(const v8s*)(p_ + 2048);                                        \
    B3 = *(const v8s*)(p_ + 3072); }

// one 16-col round: 16 MFMA (4 row-chains, g-split into 2 halves to cap
// live cf regs) + distributed dot with this wave's own kq-partial.
#define ROUND(B0, B1, B2, B3, T)                                          \
  { const float* xp_ = &xvb[((T) >> 3) & 1][((T) & 7) * 16 + l15];        \
    const float bb_ = (e == 0) ? bvec[(T) * 16 + l15] : 0.f;              \
    v4f c0, c1;                                                           \
    c0 = (v4f){0.f,0.f,0.f,0.f}; c1 = (v4f){0.f,0.f,0.f,0.f};             \
    c0 = MFMA16(a[0][0], B0, c0); c1 = MFMA16(a[1][0], B0, c1);           \
    c0 = MFMA16(a[0][1], B1, c0); c1 = MFMA16(a[1][1], B1, c1);           \
    c0 = MFMA16(a[0][2], B2, c0); c1 = MFMA16(a[1][2], B2, c1);           \
    c0 = MFMA16(a[0][3], B3, c0); c1 = MFMA16(a[1][3], B3, c1);           \
    _Pragma("unroll")                                                     \
    for (int r = 0; r < 4; ++r) {                                         \
      acc[0][r] += (c0[r] + bb_) * xp_[(     quad * 4 + r) * XR];         \
      acc[1][r] += (c1[r] + bb_) * xp_[(16 + quad * 4 + r) * XR];         \
    }                                                                     \
    c0 = (v4f){0.f,0.f,0.f,0.f}; c1 = (v4f){0.f,0.f,0.f,0.f};             \
    c0 = MFMA16(a[2][0], B0, c0); c1 = MFMA16(a[3][0], B0, c1);           \
    c0 = MFMA16(a[2][1], B1, c0); c1 = MFMA16(a[3][1], B1, c1);           \
    c0 = MFMA16(a[2][2], B2, c0); c1 = MFMA16(a[3][2], B2, c1);           \
    c0 = MFMA16(a[2][3], B3, c0); c1 = MFMA16(a[3][3], B3, c1);           \
    _Pragma("unroll")                                                     \
    for (int r = 0; r < 4; ++r) {                                         \
      acc[2][r] += (c0[r] + bb_) * xp_[(32 + quad * 4 + r) * XR];         \
      acc[3][r] += (c1[r] + bb_) * xp_[(48 + quad * 4 + r) * XR];         \
    } }

// wave e dumps its A-frags (x[64 rows][e*128..+128] == phase-e columns)
// as f32 into xvb[ph&1]. Static a-indices throughout.
#define DUMPXV(ph)                                                        \
  { float* bse_ = &xvb[(ph) & 1][0];                                      \
    _Pragma("unroll")                                                     \
    for (int g = 0; g < 4; ++g) {                                         \
      _Pragma("unroll")                                                   \
      for (int s = 0; s < 4; ++s) {                                       \
        float* d_ = bse_ + (g * 16 + l15) * XR + s * 32 + quad * 8;       \
        const v8s fr_ = a[g][s];                                          \
        float4 lo_, hi_;                                                  \
        lo_.x = b2f(fr_[0]); lo_.y = b2f(fr_[1]);                         \
        lo_.z = b2f(fr_[2]); lo_.w = b2f(fr_[3]);                         \
        hi_.x = b2f(fr_[4]); hi_.y = b2f(fr_[5]);                         \
        hi_.z = b2f(fr_[6]); hi_.w = b2f(fr_[7]);                         \
        *(float4*)d_ = lo_; *((float4*)d_ + 1) = hi_;                     \
      } } }

__global__ __launch_bounds__(512, 2)
void quad_kernel(const float* __restrict__ x, const char* __restrict__ qb,
                 const float* __restrict__ bvec, const float* __restrict__ cptr,
                 float* __restrict__ y)
{
    __shared__ __align__(16) float xvb[2][64 * XR];   // 67.6 KB, phase dbuf
    __shared__ float yred[8][64];                     //  2.0 KB

    const int tid  = threadIdx.x;
    const int lane = tid & 63;
    const int e    = tid >> 6;       // 0..7: owns k-eighth [e*128, +128)
    const int quad = lane >> 4;
    const int l15  = lane & 15;

    const int row_base = blockIdx.x * 64;

    // ---- B tile-0 loads first (in flight under the whole A prologue) ----
    v8s bA0, bA1, bA2, bA3, bB0, bB1, bB2, bB3;
    LOADB(bA0, bA1, bA2, bA3, 0);

    // ---- A prologue: x[64 rows][e's 128 k] -> a[4][4] bf16 in AGPRs ----
    // A-frag (16x16x32): m = l15, k = quad*8 + j. HBM-bound (~64 MB once).
    v8s a[4][4];
    #pragma unroll
    for (int g = 0; g < 4; ++g) {
        const float* xr = x + (size_t)(row_base + g * 16 + l15) * DD
                        + e * 128 + quad * 8;
        #pragma unroll
        for (int s = 0; s < 4; ++s) {
            const float4 f0 = *(const float4*)(xr + s * 32);
            const float4 f1 = *(const float4*)(xr + s * 32 + 4);
            v8s t;
            t[0]=f2b(f0.x); t[1]=f2b(f0.y); t[2]=f2b(f0.z); t[3]=f2b(f0.w);
            t[4]=f2b(f1.x); t[5]=f2b(f1.y); t[6]=f2b(f1.z); t[7]=f2b(f1.w);
            a[g][s] = t;
            asm volatile("" : "+a"(a[g][s]));   // steer to AGPR
        }
    }

    // phase-0 xv dump by wave 0; visible after the prologue barrier
    if (e == 0) DUMPXV(0);
    __syncthreads();

    float acc[4][4];
    #pragma unroll
    for (int g = 0; g < 4; ++g)
        #pragma unroll
        for (int r = 0; r < 4; ++r) acc[g][r] = 0.f;

    for (int t = 0; t < 64; t += 2) {
        if ((t & 7) == 0) {
            if (t) __syncthreads();            // phase boundary (8 total)
            const int ph = (t >> 3) + 1;       // next phase to dump
            if (ph < 8 && e == ph) DUMPXV(ph); // into buf[(ph)&1]: its
            // previous content (phase ph-2) is dead past this barrier;
            // readers of phase ph start only after the NEXT barrier.
        }
        // even round t: prefetch tile t+1, compute with bA
        LOADB(bB0, bB1, bB2, bB3, t + 1);
        ROUND(bA0, bA1, bA2, bA3, t);
        // odd round t+1: prefetch tile t+2, compute with bB
        if (t + 2 < 64) LOADB(bA0, bA1, bA2, bA3, t + 2);
        ROUND(bB0, bB1, bB2, bB3, t + 1);
    }

    // ---- reduce 16 l15-lanes (shfl), then 8 k-eighth waves (LDS) ----
    #pragma unroll
    for (int g = 0; g < 4; ++g)
        #pragma unroll
        for (int r = 0; r < 4; ++r) {
            float v = acc[g][r];
            v += __shfl_xor(v, 1); v += __shfl_xor(v, 2);
            v += __shfl_xor(v, 4); v += __shfl_xor(v, 8);
            if (l15 == 0)
                yred[e][g * 16 + quad * 4 + r] = v;
        }
    __syncthreads();
    if (tid < 64) {
        float s = yred[0][tid] + yred[1][tid] + yred[2][tid] + yred[3][tid]
                + yred[4][tid] + yred[5][tid] + yred[6][tid] + yred[7][tid];
        y[row_base + tid] = s + cptr[0];
    }
}

extern "C" void kernel_launch(void* const* d_in, const int* in_sizes, int n_in,
                              void* d_out, int out_size, void* d_ws, size_t ws_size,
                              hipStream_t stream)
{
    const float* x = (const float*)d_in[0];
    const float* Q = (const float*)d_in[1];
    const float* b = (const float*)d_in[2];
    const float* c = (const float*)d_in[3];
    float* y = (float*)d_out;
    char* qb = (char*)d_ws;   // 2 MB bf16 frag-ordered Q image

    cvt_kernel<<<dim3(512), dim3(256), 0, stream>>>(Q, qb);
    quad_kernel<<<dim3(256), dim3(512), 0, stream>>>(x, qb, b, c, y);
}